// Round 19
// baseline (882.588 us; speedup 1.0000x reference)
//
#include <hip/hip_runtime.h>
#include <stdint.h>
#include <stddef.h>

#define BB 8
#define TENC 200
#define UU 100
#define UP1 101
#define VP1 1025
#define ED 128
#define PD 512
#define LSTM_NWG 64
#define MTOT 161600   // 8*200*101 flattened output rows
#define MB_  20200    // rows per batch (200*101)

typedef __attribute__((ext_vector_type(8))) unsigned short ushort8;
typedef __attribute__((ext_vector_type(8))) __bf16 bf16x8;
typedef __attribute__((ext_vector_type(4))) float f32x4;

__device__ __forceinline__ float bf2f(unsigned short u){
  unsigned int x = ((unsigned int)u) << 16;
  return __builtin_bit_cast(float, x);
}
__device__ __forceinline__ unsigned short f2bf(float f){
  unsigned int x = __builtin_bit_cast(unsigned int, f);
  unsigned int r = (x + 0x7fffu + ((x >> 16) & 1u)) >> 16;
  return (unsigned short)r;
}
__device__ __forceinline__ float tanh_fast(float x){
  float e = __expf(2.0f * x);
  return 1.0f - 2.0f / (e + 1.0f);
}
__device__ __forceinline__ float sigm(float x){
  return 1.0f / (1.0f + __expf(-x));
}
__device__ __forceinline__ void gload_lds16(const unsigned short* gsrc, unsigned short* ldst){
  __builtin_amdgcn_global_load_lds((const __attribute__((address_space(1))) void*)gsrc,
                                   (__attribute__((address_space(3))) void*)ldst, 16, 0, 0);
}

// ---------------- fp32 -> bf16 convert (W_joint) ----------------
__global__ __launch_bounds__(256) void k_cvt_bf16(const float* __restrict__ src,
                                                  unsigned short* __restrict__ dst, int n){
  int i = blockIdx.x * 256 + threadIdx.x;
  if (i < n) dst[i] = f2bf(src[i]);
}

// ---------------- K1: embedding + x-part of LSTM gates ----------------
__global__ __launch_bounds__(256) void k_xgate(
    const float* __restrict__ emb, const int* __restrict__ targets,
    const float* __restrict__ W_ih, const float* __restrict__ b_ih,
    const float* __restrict__ b_hh, float* __restrict__ xg)
{
  __shared__ float e_s[BB * ED];
  const int u  = blockIdx.x >> 2;
  const int jq = blockIdx.x & 3;
  const int tid = threadIdx.x;
  for (int idx = tid; idx < BB * ED; idx += 256){
    int b = idx >> 7, e = idx & 127;
    int tok = (u == 0) ? 1024 : targets[b * UU + (u - 1)];
    e_s[idx] = emb[(size_t)tok * ED + e];
  }
  __syncthreads();
  float acc[2][BB];
  #pragma unroll
  for (int r = 0; r < 2; r++)
    #pragma unroll
    for (int b = 0; b < BB; b++) acc[r][b] = 0.0f;
  const int j0 = jq * 512 + tid;
  const float* w0p = W_ih + (size_t)j0 * ED;
  const float* w1p = W_ih + (size_t)(j0 + 256) * ED;
  for (int e = 0; e < ED; e++){
    float w0 = w0p[e], w1 = w1p[e];
    #pragma unroll
    for (int b = 0; b < BB; b++){
      float ev = e_s[b * ED + e];
      acc[0][b] = fmaf(ev, w0, acc[0][b]);
      acc[1][b] = fmaf(ev, w1, acc[1][b]);
    }
  }
  #pragma unroll
  for (int r = 0; r < 2; r++){
    int j = j0 + r * 256;
    float bias = b_ih[j] + b_hh[j];
    #pragma unroll
    for (int b = 0; b < BB; b++)
      xg[((size_t)b * UP1 + u) * 2048 + j] = acc[r][b] + bias;
  }
}

// ---------------- K2: persistent LSTM — R3 dot + padded flag-array sync ----------------
__global__ __launch_bounds__(256) void k_lstm_all(
    const float* __restrict__ xg, const float* __restrict__ W_hh,
    float* __restrict__ pred, float* __restrict__ hb, unsigned int* __restrict__ seq)
{
  __shared__ float h_s[8][520];
  __shared__ float red[32 * 257];
  __shared__ float gates_s[32][9];
  const int tid = threadIdx.x;
  const int wg  = blockIdx.x;
  const int p0  = wg * 8;
  const int jg = tid >> 5, kc = tid & 31;
  const float* wrow[4];
  #pragma unroll
  for (int r = 0; r < 4; r++){
    int jl = jg * 4 + r;
    int grow = (jl >> 3) * PD + p0 + (jl & 7);
    wrow[r] = W_hh + (size_t)grow * PD;
  }
  float c_reg = 0.0f;
  for (int u = 0; u < UP1; u++){
    float xi = 0.f, xf = 0.f, xgv = 0.f, xo = 0.f;
    if (tid < 64){
      int pl = tid >> 3, b = tid & 7;
      const float* xr = xg + ((size_t)(b * UP1 + u)) * 2048;
      int p = p0 + pl;
      xi = xr[p]; xf = xr[512 + p]; xgv = xr[1024 + p]; xo = xr[1536 + p];
    }
    if (u > 0){
      if (tid < 64){
        while (1){
          unsigned int v = __hip_atomic_load(&seq[tid * 16], __ATOMIC_RELAXED, __HIP_MEMORY_SCOPE_AGENT);
          if (__all(v >= (unsigned int)u)) break;
          __builtin_amdgcn_s_sleep(1);
        }
      }
      __syncthreads();
      const float* hsrc = hb + ((u - 1) & 1) * 4096;
      float tmp[16];
      #pragma unroll
      for (int j = 0; j < 16; j++)
        tmp[j] = __hip_atomic_load(hsrc + tid + 256 * j,
                                   __ATOMIC_RELAXED, __HIP_MEMORY_SCOPE_AGENT);
      #pragma unroll
      for (int j = 0; j < 16; j++){
        int i = tid + 256 * j;
        h_s[i >> 9][i & 511] = tmp[j];
      }
    } else {
      for (int i = tid; i < 8 * PD; i += 256) h_s[i >> 9][i & 511] = 0.0f;
    }
    __syncthreads();
    float acc[4][BB];
    #pragma unroll
    for (int r = 0; r < 4; r++)
      #pragma unroll
      for (int b = 0; b < BB; b++) acc[r][b] = 0.0f;
    for (int i = 0; i < 16; i++){
      int k = kc + 32 * i;
      float hv[BB];
      #pragma unroll
      for (int b = 0; b < BB; b++) hv[b] = h_s[b][k];
      #pragma unroll
      for (int r = 0; r < 4; r++){
        float wv = wrow[r][k];
        #pragma unroll
        for (int b = 0; b < BB; b++) acc[r][b] = fmaf(hv[b], wv, acc[r][b]);
      }
    }
    #pragma unroll
    for (int r = 0; r < 4; r++)
      #pragma unroll
      for (int b = 0; b < BB; b++)
        red[kc * 257 + jg * 32 + r * 8 + b] = acc[r][b];
    __syncthreads();
    {
      int jl = tid >> 3, b = tid & 7;
      float s = 0.0f;
      #pragma unroll
      for (int kk = 0; kk < 32; kk++)
        s += red[kk * 257 + (jl >> 2) * 32 + (jl & 3) * 8 + b];
      gates_s[jl][b] = s;
    }
    __syncthreads();
    if (tid < 64){
      int pl = tid >> 3, b2 = tid & 7;
      int p = p0 + pl;
      float gi = gates_s[0  + pl][b2] + xi;
      float gf = gates_s[8  + pl][b2] + xf;
      float gg = gates_s[16 + pl][b2] + xgv;
      float go = gates_s[24 + pl][b2] + xo;
      float iv = sigm(gi), fv = sigm(gf), ov = sigm(go);
      c_reg = fv * c_reg + iv * tanh_fast(gg);
      float hval = ov * tanh_fast(c_reg);
      __hip_atomic_store(hb + (u & 1) * 4096 + b2 * 512 + p, hval,
                         __ATOMIC_RELAXED, __HIP_MEMORY_SCOPE_AGENT);
      pred[((size_t)(b2 * UP1 + u)) * PD + p] = hval;
    }
    if (u < UP1 - 1 && tid == 0){
      asm volatile("s_waitcnt vmcnt(0)" ::: "memory");  // wave-0 h stores retired
      __hip_atomic_store(&seq[wg * 16], (unsigned int)(u + 1),
                         __ATOMIC_RELAXED, __HIP_MEMORY_SCOPE_AGENT);
    }
  }
}

// ---------------- K3: fp32 GEMM (A @ W^T + bias) -> bf16 out ----------------
__global__ __launch_bounds__(256) void k_gemm_bias_bf16(
    const float* __restrict__ A, const float* __restrict__ W,
    const float* __restrict__ bias, unsigned short* __restrict__ out, int M)
{
  __shared__ float a_s[16][68];
  __shared__ float b_s[16][68];
  const int m0 = blockIdx.x * 64, n0 = blockIdx.y * 64;
  const int tid = threadIdx.x;
  const int tx = tid & 15, ty = tid >> 4;
  float acc[4][4];
  #pragma unroll
  for (int i2 = 0; i2 < 4; i2++)
    #pragma unroll
    for (int j2 = 0; j2 < 4; j2++) acc[i2][j2] = 0.0f;
  for (int k0 = 0; k0 < 512; k0 += 16){
    int mm = tid >> 2, k4 = (tid & 3) * 4;
    int row = m0 + mm; if (row >= M) row = M - 1;
    float4 av = *(const float4*)(A + (size_t)row * 512 + k0 + k4);
    a_s[k4 + 0][mm] = av.x; a_s[k4 + 1][mm] = av.y;
    a_s[k4 + 2][mm] = av.z; a_s[k4 + 3][mm] = av.w;
    float4 bv = *(const float4*)(W + (size_t)(n0 + mm) * 512 + k0 + k4);
    b_s[k4 + 0][mm] = bv.x; b_s[k4 + 1][mm] = bv.y;
    b_s[k4 + 2][mm] = bv.z; b_s[k4 + 3][mm] = bv.w;
    __syncthreads();
    #pragma unroll
    for (int k = 0; k < 16; k++){
      float4 a4 = *(const float4*)&a_s[k][ty * 4];
      float4 b4 = *(const float4*)&b_s[k][tx * 4];
      float aa[4] = {a4.x, a4.y, a4.z, a4.w};
      float bb[4] = {b4.x, b4.y, b4.z, b4.w};
      #pragma unroll
      for (int i2 = 0; i2 < 4; i2++)
        #pragma unroll
        for (int j2 = 0; j2 < 4; j2++)
          acc[i2][j2] = fmaf(aa[i2], bb[j2], acc[i2][j2]);
    }
    __syncthreads();
  }
  #pragma unroll
  for (int i2 = 0; i2 < 4; i2++){
    int m = m0 + ty * 4 + i2;
    if (m < M){
      #pragma unroll
      for (int j2 = 0; j2 < 4; j2++){
        int n = n0 + tx * 4 + j2;
        out[(size_t)m * 512 + n] = f2bf(acc[i2][j2] + bias[n]);
      }
    }
  }
}

// ---------------- K4a: precompute A = tanh(fe+fp) bf16, + fused blank column ----------------
__global__ __launch_bounds__(256) void k_tanhA(
    const unsigned short* __restrict__ fe, const unsigned short* __restrict__ fp,
    const unsigned short* __restrict__ wj, const float* __restrict__ bj,
    unsigned short* __restrict__ Aout, float* __restrict__ out,
    int m_base, int M_cnt)
{
  const int tid = threadIdx.x;
  const int mlocal = blockIdx.x * 4 + (tid >> 6);
  if (mlocal >= M_cnt) return;
  const int l = tid & 63;
  const int m = m_base + mlocal;
  const int q = m / 101;            // b*200 + t
  const int u = m - q * 101;
  const int b = q / 200;
  ushort8 f8 = *(const ushort8*)(fe + (size_t)q * 512 + l * 8);
  ushort8 p8 = *(const ushort8*)(fp + (size_t)(b * 101 + u) * 512 + l * 8);
  ushort8 w8 = *(const ushort8*)(wj + (size_t)1024 * 512 + l * 8);
  ushort8 a;
  float s = 0.0f;
  #pragma unroll
  for (int e = 0; e < 8; e++){
    float v = tanh_fast(bf2f(f8[e]) + bf2f(p8[e]));
    a[e] = f2bf(v);
    s += v * bf2f(w8[e]);
  }
  *(ushort8*)(Aout + (size_t)mlocal * 512 + l * 8) = a;
  #pragma unroll
  for (int off = 1; off < 64; off <<= 1) s += __shfl_xor(s, off);
  if (l == 0) out[(size_t)m * VP1 + 1024] = s + bj[1024];
}

// ---------------- K4b: joint GEMM, XCD-swizzled grid, BK=32, 3-buffer depth-2 pipeline ----
// Per iter: {issue stage(kc+2) -> vmcnt(8) -> barrier -> MFMA -> barrier}.
// Awaited stage was issued 2 iterations (~500cyc) ago -> wait ~free. 48KB LDS -> 3 blk/CU.
__global__ __launch_bounds__(256, 3) void k_joint7s(
    const unsigned short* __restrict__ A, const unsigned short* __restrict__ wj,
    const float* __restrict__ bj, float* __restrict__ out,
    int m_base, int M_cnt, int nmt)
{
  __shared__ unsigned short A_s[3][128 * 32];   // 3 x 8KB
  __shared__ unsigned short B_s[3][128 * 32];   // 3 x 8KB
  const int bid = blockIdx.x;
  const int mt  = (bid >> 6) * 8 + (bid & 7);   // m-tile
  if (mt >= nmt) return;
  const int m0 = mt * 128;
  const int n0 = ((bid >> 3) & 7) * 128;
  const int tid = threadIdx.x;
  const int w = tid >> 6, l = tid & 63;
  const int l15 = l & 15, lg = l >> 4;
  const int wr = w >> 1, wc = w & 1;

  // stage one BK=32 chunk into buffer buf: 4 gload_lds per wave (2 A + 2 B)
  auto stage = [&](int buf, int kc){
    #pragma unroll
    for (int i = 0; i < 2; i++){
      int sbase = i * 256 + w * 64;            // wave-uniform slot base
      int slot  = sbase + l;
      int r  = slot >> 2;                      // row 0..127
      int cs = slot & 3;                       // 16B sub-chunk 0..3
      int col8 = cs ^ ((r >> 1) & 3);          // pre-swizzled source
      int ra = m0 + r; if (ra >= M_cnt) ra = M_cnt - 1;
      gload_lds16(A + (size_t)ra * 512 + kc * 32 + col8 * 8,
                  (unsigned short*)A_s[buf] + (size_t)sbase * 8);
      gload_lds16(wj + (size_t)(n0 + r) * 512 + kc * 32 + col8 * 8,
                  (unsigned short*)B_s[buf] + (size_t)sbase * 8);
    }
  };

  stage(0, 0);
  stage(1, 1);   // depth-2 prologue: 8 loads in flight

  f32x4 acc[4][4];
  #pragma unroll
  for (int fr = 0; fr < 4; fr++)
    #pragma unroll
    for (int fc = 0; fc < 4; fc++)
      acc[fr][fc] = (f32x4){0.f, 0.f, 0.f, 0.f};

  for (int kc = 0; kc < 16; kc++){
    const int buf = kc % 3;
    // buf (kc+2)%3 was last ds_read at iter kc-1; its post-MFMA barrier precedes this issue.
    if (kc < 14){
      stage((kc + 2) % 3, kc + 2);                       // in flight: 12
      asm volatile("s_waitcnt vmcnt(8)" ::: "memory");   // stage(kc) (2 iters old) landed
    } else if (kc == 14){
      asm volatile("s_waitcnt vmcnt(4)" ::: "memory");   // stage(14) landed
    } else {
      asm volatile("s_waitcnt vmcnt(0)" ::: "memory");   // stage(15) landed
    }
    __builtin_amdgcn_s_barrier();                        // all waves' stage(kc) chunks resident

    bf16x8 afr[4], bfr[4];
    #pragma unroll
    for (int f = 0; f < 4; f++){
      int ra = wr * 64 + f * 16 + l15;
      int bya = ra * 64 + ((lg ^ ((ra >> 1) & 3)) * 16);
      afr[f] = __builtin_bit_cast(bf16x8, *(const ushort8*)((const char*)A_s[buf] + bya));
      int rb = wc * 64 + f * 16 + l15;
      int byb = rb * 64 + ((lg ^ ((rb >> 1) & 3)) * 16);
      bfr[f] = __builtin_bit_cast(bf16x8, *(const ushort8*)((const char*)B_s[buf] + byb));
    }
    #pragma unroll
    for (int fr = 0; fr < 4; fr++)
      #pragma unroll
      for (int fc = 0; fc < 4; fc++)
        acc[fr][fc] = __builtin_amdgcn_mfma_f32_16x16x32_bf16(bfr[fc], afr[fr], acc[fr][fc], 0, 0, 0);
    __builtin_amdgcn_s_barrier();                        // all waves done reading buf
  }

  // epilogue: C reg-dim = n (col), lane l15 = m (row)
  #pragma unroll
  for (int fr = 0; fr < 4; fr++){
    int mloc = m0 + wr * 64 + fr * 16 + l15;
    if (mloc < M_cnt){
      float* orow = out + (size_t)(m_base + mloc) * VP1;
      #pragma unroll
      for (int fc = 0; fc < 4; fc++){
        int col = n0 + wc * 64 + fc * 16 + lg * 4;
        float4 bv = *(const float4*)(bj + col);
        f32x4 v = acc[fr][fc];
        float4 st = {v[0] + bv.x, v[1] + bv.y, v[2] + bv.z, v[3] + bv.w};
        *(float4*)(orow + col) = st;
      }
    }
  }
}

extern "C" void kernel_launch(void* const* d_in, const int* in_sizes, int n_in,
                              void* d_out, int out_size, void* d_ws, size_t ws_size,
                              hipStream_t stream) {
  const float* enc_out = (const float*)d_in[0];
  const int*   targets = (const int*)d_in[1];
  const float* emb     = (const float*)d_in[3];
  const float* W_ih    = (const float*)d_in[4];
  const float* W_hh    = (const float*)d_in[5];
  const float* b_ih    = (const float*)d_in[6];
  const float* b_hh    = (const float*)d_in[7];
  const float* W_enc   = (const float*)d_in[8];
  const float* b_enc   = (const float*)d_in[9];
  const float* W_pred  = (const float*)d_in[10];
  const float* b_pred  = (const float*)d_in[11];
  const float* W_joint = (const float*)d_in[12];
  const float* b_joint = (const float*)d_in[13];
  float* out = (float*)d_out;

  char* ws = (char*)d_ws;
  float* xg            = (float*)(ws + 0);                  // 6,619,136 B
  float* pred          = (float*)(ws + 6619136);            // 1,654,784 B
  unsigned short* feb  = (unsigned short*)(ws + 8273920);   // 1,638,400 B
  unsigned short* fpb  = (unsigned short*)(ws + 9912320);   //   827,392 B
  unsigned short* wjb  = (unsigned short*)(ws + 10739712);  // 1,049,600 B
  float* hb            = (float*)(ws + 11789312);           //    32,768 B
  unsigned int* seq    = (unsigned int*)(ws + 11822080);    //     4,096 B (64 x 64B lines)
  unsigned short* Abuf = (unsigned short*)(ws + 11827200);  // A workspace
  const size_t FULL_NEED  = 11827200 + (size_t)MTOT * 512 * 2;  // ~177.3 MB
  const size_t BATCH_NEED = 11827200 + (size_t)MB_  * 512 * 2;  // ~32.5 MB

  (void)hipMemsetAsync(seq, 0, 4096, stream);
  hipLaunchKernelGGL(k_cvt_bf16, dim3((VP1 * 512 + 255) / 256), dim3(256), 0, stream,
                     W_joint, wjb, VP1 * 512);
  hipLaunchKernelGGL(k_xgate, dim3(404), dim3(256), 0, stream,
                     emb, targets, W_ih, b_ih, b_hh, xg);
  hipLaunchKernelGGL(k_gemm_bias_bf16, dim3(25, 8), dim3(256), 0, stream,
                     enc_out, W_enc, b_enc, feb, 1600);
  hipLaunchKernelGGL(k_lstm_all, dim3(LSTM_NWG), dim3(256), 0, stream,
                     xg, W_hh, pred, hb, seq);
  hipLaunchKernelGGL(k_gemm_bias_bf16, dim3(13, 8), dim3(256), 0, stream,
                     pred, W_pred, b_pred, fpb, 808);

  if (ws_size >= FULL_NEED){
    const int nmt = 1263;                       // ceil(161600/128)
    const int grid = 8 * 8 * ((nmt + 7) / 8);   // 10112
    hipLaunchKernelGGL(k_tanhA, dim3(MTOT / 4), dim3(256), 0, stream,
                       feb, fpb, wjb, b_joint, Abuf, out, 0, MTOT);
    hipLaunchKernelGGL(k_joint7s, dim3(grid), dim3(256), 0, stream,
                       Abuf, wjb, b_joint, out, 0, MTOT, nmt);
  } else if (ws_size >= BATCH_NEED){
    const int nmt = 158;                        // ceil(20200/128)
    const int grid = 8 * 8 * ((nmt + 7) / 8);   // 1280
    for (int b = 0; b < 8; b++){
      hipLaunchKernelGGL(k_tanhA, dim3(MB_ / 4), dim3(256), 0, stream,
                         feb, fpb, wjb, b_joint, Abuf, out, b * MB_, MB_);
      hipLaunchKernelGGL(k_joint7s, dim3(grid), dim3(256), 0, stream,
                         Abuf, wjb, b_joint, out, b * MB_, MB_, nmt);
    }
  } else {
    const int nmt = 40;                         // ceil(5050/128)
    const int grid = 8 * 8 * ((nmt + 7) / 8);   // 320
    for (int c = 0; c < 32; c++){
      hipLaunchKernelGGL(k_tanhA, dim3(5050 / 2, 1), dim3(256), 0, stream,
                         feb, fpb, wjb, b_joint, Abuf, out, c * 5050, 5050);
      hipLaunchKernelGGL(k_joint7s, dim3(grid), dim3(256), 0, stream,
                         Abuf, wjb, b_joint, out, c * 5050, 5050, nmt);
    }
  }
}

// Round 20
// 862.260 us; speedup vs baseline: 1.0236x; 1.0236x over previous
//
#include <hip/hip_runtime.h>
#include <stdint.h>
#include <stddef.h>

#define BB 8
#define TENC 200
#define UU 100
#define UP1 101
#define VP1 1025
#define ED 128
#define PD 512
#define LSTM_NWG 64
#define MTOT 161600   // 8*200*101 flattened output rows
#define MB_  20200    // rows per batch (200*101)

typedef __attribute__((ext_vector_type(8))) unsigned short ushort8;
typedef __attribute__((ext_vector_type(8))) __bf16 bf16x8;
typedef __attribute__((ext_vector_type(4))) float f32x4;

__device__ __forceinline__ float bf2f(unsigned short u){
  unsigned int x = ((unsigned int)u) << 16;
  return __builtin_bit_cast(float, x);
}
__device__ __forceinline__ unsigned short f2bf(float f){
  unsigned int x = __builtin_bit_cast(unsigned int, f);
  unsigned int r = (x + 0x7fffu + ((x >> 16) & 1u)) >> 16;
  return (unsigned short)r;
}
__device__ __forceinline__ float tanh_fast(float x){
  float e = __expf(2.0f * x);
  return 1.0f - 2.0f / (e + 1.0f);
}
__device__ __forceinline__ float sigm(float x){
  return 1.0f / (1.0f + __expf(-x));
}
__device__ __forceinline__ void gload_lds16(const unsigned short* gsrc, unsigned short* ldst){
  __builtin_amdgcn_global_load_lds((const __attribute__((address_space(1))) void*)gsrc,
                                   (__attribute__((address_space(3))) void*)ldst, 16, 0, 0);
}

// ---------------- fp32 -> bf16 convert (W_joint) ----------------
__global__ __launch_bounds__(256) void k_cvt_bf16(const float* __restrict__ src,
                                                  unsigned short* __restrict__ dst, int n){
  int i = blockIdx.x * 256 + threadIdx.x;
  if (i < n) dst[i] = f2bf(src[i]);
}

// ---------------- K1: embedding + x-part of LSTM gates ----------------
__global__ __launch_bounds__(256) void k_xgate(
    const float* __restrict__ emb, const int* __restrict__ targets,
    const float* __restrict__ W_ih, const float* __restrict__ b_ih,
    const float* __restrict__ b_hh, float* __restrict__ xg)
{
  __shared__ float e_s[BB * ED];
  const int u  = blockIdx.x >> 2;
  const int jq = blockIdx.x & 3;
  const int tid = threadIdx.x;
  for (int idx = tid; idx < BB * ED; idx += 256){
    int b = idx >> 7, e = idx & 127;
    int tok = (u == 0) ? 1024 : targets[b * UU + (u - 1)];
    e_s[idx] = emb[(size_t)tok * ED + e];
  }
  __syncthreads();
  float acc[2][BB];
  #pragma unroll
  for (int r = 0; r < 2; r++)
    #pragma unroll
    for (int b = 0; b < BB; b++) acc[r][b] = 0.0f;
  const int j0 = jq * 512 + tid;
  const float* w0p = W_ih + (size_t)j0 * ED;
  const float* w1p = W_ih + (size_t)(j0 + 256) * ED;
  for (int e = 0; e < ED; e++){
    float w0 = w0p[e], w1 = w1p[e];
    #pragma unroll
    for (int b = 0; b < BB; b++){
      float ev = e_s[b * ED + e];
      acc[0][b] = fmaf(ev, w0, acc[0][b]);
      acc[1][b] = fmaf(ev, w1, acc[1][b]);
    }
  }
  #pragma unroll
  for (int r = 0; r < 2; r++){
    int j = j0 + r * 256;
    float bias = b_ih[j] + b_hh[j];
    #pragma unroll
    for (int b = 0; b < BB; b++)
      xg[((size_t)b * UP1 + u) * 2048 + j] = acc[r][b] + bias;
  }
}

// ---------------- K2: persistent LSTM — R3 dot + padded flag-array sync ----------------
__global__ __launch_bounds__(256) void k_lstm_all(
    const float* __restrict__ xg, const float* __restrict__ W_hh,
    float* __restrict__ pred, float* __restrict__ hb, unsigned int* __restrict__ seq)
{
  __shared__ float h_s[8][520];
  __shared__ float red[32 * 257];
  __shared__ float gates_s[32][9];
  const int tid = threadIdx.x;
  const int wg  = blockIdx.x;
  const int p0  = wg * 8;
  const int jg = tid >> 5, kc = tid & 31;
  const float* wrow[4];
  #pragma unroll
  for (int r = 0; r < 4; r++){
    int jl = jg * 4 + r;
    int grow = (jl >> 3) * PD + p0 + (jl & 7);
    wrow[r] = W_hh + (size_t)grow * PD;
  }
  float c_reg = 0.0f;
  for (int u = 0; u < UP1; u++){
    float xi = 0.f, xf = 0.f, xgv = 0.f, xo = 0.f;
    if (tid < 64){
      int pl = tid >> 3, b = tid & 7;
      const float* xr = xg + ((size_t)(b * UP1 + u)) * 2048;
      int p = p0 + pl;
      xi = xr[p]; xf = xr[512 + p]; xgv = xr[1024 + p]; xo = xr[1536 + p];
    }
    if (u > 0){
      if (tid < 64){
        while (1){
          unsigned int v = __hip_atomic_load(&seq[tid * 16], __ATOMIC_RELAXED, __HIP_MEMORY_SCOPE_AGENT);
          if (__all(v >= (unsigned int)u)) break;
          __builtin_amdgcn_s_sleep(1);
        }
      }
      __syncthreads();
      const float* hsrc = hb + ((u - 1) & 1) * 4096;
      float tmp[16];
      #pragma unroll
      for (int j = 0; j < 16; j++)
        tmp[j] = __hip_atomic_load(hsrc + tid + 256 * j,
                                   __ATOMIC_RELAXED, __HIP_MEMORY_SCOPE_AGENT);
      #pragma unroll
      for (int j = 0; j < 16; j++){
        int i = tid + 256 * j;
        h_s[i >> 9][i & 511] = tmp[j];
      }
    } else {
      for (int i = tid; i < 8 * PD; i += 256) h_s[i >> 9][i & 511] = 0.0f;
    }
    __syncthreads();
    float acc[4][BB];
    #pragma unroll
    for (int r = 0; r < 4; r++)
      #pragma unroll
      for (int b = 0; b < BB; b++) acc[r][b] = 0.0f;
    for (int i = 0; i < 16; i++){
      int k = kc + 32 * i;
      float hv[BB];
      #pragma unroll
      for (int b = 0; b < BB; b++) hv[b] = h_s[b][k];
      #pragma unroll
      for (int r = 0; r < 4; r++){
        float wv = wrow[r][k];
        #pragma unroll
        for (int b = 0; b < BB; b++) acc[r][b] = fmaf(hv[b], wv, acc[r][b]);
      }
    }
    #pragma unroll
    for (int r = 0; r < 4; r++)
      #pragma unroll
      for (int b = 0; b < BB; b++)
        red[kc * 257 + jg * 32 + r * 8 + b] = acc[r][b];
    __syncthreads();
    {
      int jl = tid >> 3, b = tid & 7;
      float s = 0.0f;
      #pragma unroll
      for (int kk = 0; kk < 32; kk++)
        s += red[kk * 257 + (jl >> 2) * 32 + (jl & 3) * 8 + b];
      gates_s[jl][b] = s;
    }
    __syncthreads();
    if (tid < 64){
      int pl = tid >> 3, b2 = tid & 7;
      int p = p0 + pl;
      float gi = gates_s[0  + pl][b2] + xi;
      float gf = gates_s[8  + pl][b2] + xf;
      float gg = gates_s[16 + pl][b2] + xgv;
      float go = gates_s[24 + pl][b2] + xo;
      float iv = sigm(gi), fv = sigm(gf), ov = sigm(go);
      c_reg = fv * c_reg + iv * tanh_fast(gg);
      float hval = ov * tanh_fast(c_reg);
      __hip_atomic_store(hb + (u & 1) * 4096 + b2 * 512 + p, hval,
                         __ATOMIC_RELAXED, __HIP_MEMORY_SCOPE_AGENT);
      pred[((size_t)(b2 * UP1 + u)) * PD + p] = hval;
    }
    if (u < UP1 - 1 && tid == 0){
      asm volatile("s_waitcnt vmcnt(0)" ::: "memory");  // wave-0 h stores retired
      __hip_atomic_store(&seq[wg * 16], (unsigned int)(u + 1),
                         __ATOMIC_RELAXED, __HIP_MEMORY_SCOPE_AGENT);
    }
  }
}

// ---------------- K3: fp32 GEMM (A @ W^T + bias) -> bf16 out ----------------
__global__ __launch_bounds__(256) void k_gemm_bias_bf16(
    const float* __restrict__ A, const float* __restrict__ W,
    const float* __restrict__ bias, unsigned short* __restrict__ out, int M)
{
  __shared__ float a_s[16][68];
  __shared__ float b_s[16][68];
  const int m0 = blockIdx.x * 64, n0 = blockIdx.y * 64;
  const int tid = threadIdx.x;
  const int tx = tid & 15, ty = tid >> 4;
  float acc[4][4];
  #pragma unroll
  for (int i2 = 0; i2 < 4; i2++)
    #pragma unroll
    for (int j2 = 0; j2 < 4; j2++) acc[i2][j2] = 0.0f;
  for (int k0 = 0; k0 < 512; k0 += 16){
    int mm = tid >> 2, k4 = (tid & 3) * 4;
    int row = m0 + mm; if (row >= M) row = M - 1;
    float4 av = *(const float4*)(A + (size_t)row * 512 + k0 + k4);
    a_s[k4 + 0][mm] = av.x; a_s[k4 + 1][mm] = av.y;
    a_s[k4 + 2][mm] = av.z; a_s[k4 + 3][mm] = av.w;
    float4 bv = *(const float4*)(W + (size_t)(n0 + mm) * 512 + k0 + k4);
    b_s[k4 + 0][mm] = bv.x; b_s[k4 + 1][mm] = bv.y;
    b_s[k4 + 2][mm] = bv.z; b_s[k4 + 3][mm] = bv.w;
    __syncthreads();
    #pragma unroll
    for (int k = 0; k < 16; k++){
      float4 a4 = *(const float4*)&a_s[k][ty * 4];
      float4 b4 = *(const float4*)&b_s[k][tx * 4];
      float aa[4] = {a4.x, a4.y, a4.z, a4.w};
      float bb[4] = {b4.x, b4.y, b4.z, b4.w};
      #pragma unroll
      for (int i2 = 0; i2 < 4; i2++)
        #pragma unroll
        for (int j2 = 0; j2 < 4; j2++)
          acc[i2][j2] = fmaf(aa[i2], bb[j2], acc[i2][j2]);
    }
    __syncthreads();
  }
  #pragma unroll
  for (int i2 = 0; i2 < 4; i2++){
    int m = m0 + ty * 4 + i2;
    if (m < M){
      #pragma unroll
      for (int j2 = 0; j2 < 4; j2++){
        int n = n0 + tx * 4 + j2;
        out[(size_t)m * 512 + n] = f2bf(acc[i2][j2] + bias[n]);
      }
    }
  }
}

// ---------------- K4a: precompute A = tanh(fe+fp) bf16, + fused blank column ----------------
__global__ __launch_bounds__(256) void k_tanhA(
    const unsigned short* __restrict__ fe, const unsigned short* __restrict__ fp,
    const unsigned short* __restrict__ wj, const float* __restrict__ bj,
    unsigned short* __restrict__ Aout, float* __restrict__ out,
    int m_base, int M_cnt)
{
  const int tid = threadIdx.x;
  const int mlocal = blockIdx.x * 4 + (tid >> 6);
  if (mlocal >= M_cnt) return;
  const int l = tid & 63;
  const int m = m_base + mlocal;
  const int q = m / 101;            // b*200 + t
  const int u = m - q * 101;
  const int b = q / 200;
  ushort8 f8 = *(const ushort8*)(fe + (size_t)q * 512 + l * 8);
  ushort8 p8 = *(const ushort8*)(fp + (size_t)(b * 101 + u) * 512 + l * 8);
  ushort8 w8 = *(const ushort8*)(wj + (size_t)1024 * 512 + l * 8);
  ushort8 a;
  float s = 0.0f;
  #pragma unroll
  for (int e = 0; e < 8; e++){
    float v = tanh_fast(bf2f(f8[e]) + bf2f(p8[e]));
    a[e] = f2bf(v);
    s += v * bf2f(w8[e]);
  }
  *(ushort8*)(Aout + (size_t)mlocal * 512 + l * 8) = a;
  #pragma unroll
  for (int off = 1; off < 64; off <<= 1) s += __shfl_xor(s, off);
  if (l == 0) out[(size_t)m * VP1 + 1024] = s + bj[1024];
}

// ---------------- K4b: joint GEMM, XCD-swizzled grid, BK=32, 4 blocks/CU,
//                  counted-vmcnt pipeline (stage(kc+1) stays in flight across barriers) ----
__global__ __launch_bounds__(256, 4) void k_joint7s(
    const unsigned short* __restrict__ A, const unsigned short* __restrict__ wj,
    const float* __restrict__ bj, float* __restrict__ out,
    int m_base, int M_cnt, int nmt)
{
  __shared__ unsigned short A_s[2][128 * 32];   // 2 x 8KB
  __shared__ unsigned short B_s[2][128 * 32];   // 2 x 8KB
  const int bid = blockIdx.x;
  const int mt  = (bid >> 6) * 8 + (bid & 7);   // m-tile
  if (mt >= nmt) return;
  const int m0 = mt * 128;
  const int n0 = ((bid >> 3) & 7) * 128;
  const int tid = threadIdx.x;
  const int w = tid >> 6, l = tid & 63;
  const int l15 = l & 15, lg = l >> 4;
  const int wr = w >> 1, wc = w & 1;

  auto stage = [&](int buf, int kc){
    #pragma unroll
    for (int i = 0; i < 2; i++){
      int sbase = i * 256 + w * 64;            // wave-uniform slot base
      int slot  = sbase + l;
      int r  = slot >> 2;                      // row 0..127
      int cs = slot & 3;                       // 16B sub-chunk 0..3
      int col8 = cs ^ ((r >> 1) & 3);          // pre-swizzled source
      int ra = m0 + r; if (ra >= M_cnt) ra = M_cnt - 1;
      gload_lds16(A + (size_t)ra * 512 + kc * 32 + col8 * 8,
                  (unsigned short*)A_s[buf] + (size_t)sbase * 8);
      gload_lds16(wj + (size_t)(n0 + r) * 512 + kc * 32 + col8 * 8,
                  (unsigned short*)B_s[buf] + (size_t)sbase * 8);
    }
  };

  stage(0, 0);
  __syncthreads();   // drains vmcnt: buf0 resident for all waves

  f32x4 acc[4][4];
  #pragma unroll
  for (int fr = 0; fr < 4; fr++)
    #pragma unroll
    for (int fc = 0; fc < 4; fc++)
      acc[fr][fc] = (f32x4){0.f, 0.f, 0.f, 0.f};

  for (int kc = 0; kc < 16; kc++){
    const int buf = kc & 1;
    // buf^1 was last ds_read at iter kc-1; that iter's post-MFMA barrier precedes this issue.
    if (kc < 15){
      stage(buf ^ 1, kc + 1);                            // 4 loads, stay in flight
      asm volatile("s_waitcnt vmcnt(4)" ::: "memory");   // stage(kc) (issued last iter) landed
    } else {
      asm volatile("s_waitcnt vmcnt(0)" ::: "memory");
    }
    __builtin_amdgcn_s_barrier();                        // all waves' stage(kc) chunks resident

    bf16x8 afr[4], bfr[4];
    #pragma unroll
    for (int f = 0; f < 4; f++){
      int ra = wr * 64 + f * 16 + l15;
      int bya = ra * 64 + ((lg ^ ((ra >> 1) & 3)) * 16);
      afr[f] = __builtin_bit_cast(bf16x8, *(const ushort8*)((const char*)A_s[buf] + bya));
      int rb = wc * 64 + f * 16 + l15;
      int byb = rb * 64 + ((lg ^ ((rb >> 1) & 3)) * 16);
      bfr[f] = __builtin_bit_cast(bf16x8, *(const ushort8*)((const char*)B_s[buf] + byb));
    }
    #pragma unroll
    for (int fr = 0; fr < 4; fr++)
      #pragma unroll
      for (int fc = 0; fc < 4; fc++)
        acc[fr][fc] = __builtin_amdgcn_mfma_f32_16x16x32_bf16(bfr[fc], afr[fr], acc[fr][fc], 0, 0, 0);
    __builtin_amdgcn_s_barrier();                        // all waves done reading buf
  }

  // epilogue: C reg-dim = n (col), lane l15 = m (row)
  #pragma unroll
  for (int fr = 0; fr < 4; fr++){
    int mloc = m0 + wr * 64 + fr * 16 + l15;
    if (mloc < M_cnt){
      float* orow = out + (size_t)(m_base + mloc) * VP1;
      #pragma unroll
      for (int fc = 0; fc < 4; fc++){
        int col = n0 + wc * 64 + fc * 16 + lg * 4;
        float4 bv = *(const float4*)(bj + col);
        f32x4 v = acc[fr][fc];
        float4 st = {v[0] + bv.x, v[1] + bv.y, v[2] + bv.z, v[3] + bv.w};
        *(float4*)(orow + col) = st;
      }
    }
  }
}

extern "C" void kernel_launch(void* const* d_in, const int* in_sizes, int n_in,
                              void* d_out, int out_size, void* d_ws, size_t ws_size,
                              hipStream_t stream) {
  const float* enc_out = (const float*)d_in[0];
  const int*   targets = (const int*)d_in[1];
  const float* emb     = (const float*)d_in[3];
  const float* W_ih    = (const float*)d_in[4];
  const float* W_hh    = (const float*)d_in[5];
  const float* b_ih    = (const float*)d_in[6];
  const float* b_hh    = (const float*)d_in[7];
  const float* W_enc   = (const float*)d_in[8];
  const float* b_enc   = (const float*)d_in[9];
  const float* W_pred  = (const float*)d_in[10];
  const float* b_pred  = (const float*)d_in[11];
  const float* W_joint = (const float*)d_in[12];
  const float* b_joint = (const float*)d_in[13];
  float* out = (float*)d_out;

  char* ws = (char*)d_ws;
  float* xg            = (float*)(ws + 0);                  // 6,619,136 B
  float* pred          = (float*)(ws + 6619136);            // 1,654,784 B
  unsigned short* feb  = (unsigned short*)(ws + 8273920);   // 1,638,400 B
  unsigned short* fpb  = (unsigned short*)(ws + 9912320);   //   827,392 B
  unsigned short* wjb  = (unsigned short*)(ws + 10739712);  // 1,049,600 B
  float* hb            = (float*)(ws + 11789312);           //    32,768 B
  unsigned int* seq    = (unsigned int*)(ws + 11822080);    //     4,096 B (64 x 64B lines)
  unsigned short* Abuf = (unsigned short*)(ws + 11827200);  // A workspace
  const size_t FULL_NEED  = 11827200 + (size_t)MTOT * 512 * 2;  // ~177.3 MB
  const size_t BATCH_NEED = 11827200 + (size_t)MB_  * 512 * 2;  // ~32.5 MB

  (void)hipMemsetAsync(seq, 0, 4096, stream);
  hipLaunchKernelGGL(k_cvt_bf16, dim3((VP1 * 512 + 255) / 256), dim3(256), 0, stream,
                     W_joint, wjb, VP1 * 512);
  hipLaunchKernelGGL(k_xgate, dim3(404), dim3(256), 0, stream,
                     emb, targets, W_ih, b_ih, b_hh, xg);
  hipLaunchKernelGGL(k_gemm_bias_bf16, dim3(25, 8), dim3(256), 0, stream,
                     enc_out, W_enc, b_enc, feb, 1600);
  hipLaunchKernelGGL(k_lstm_all, dim3(LSTM_NWG), dim3(256), 0, stream,
                     xg, W_hh, pred, hb, seq);
  hipLaunchKernelGGL(k_gemm_bias_bf16, dim3(13, 8), dim3(256), 0, stream,
                     pred, W_pred, b_pred, fpb, 808);

  if (ws_size >= FULL_NEED){
    const int nmt = 1263;                       // ceil(161600/128)
    const int grid = 8 * 8 * ((nmt + 7) / 8);   // 10112
    hipLaunchKernelGGL(k_tanhA, dim3(MTOT / 4), dim3(256), 0, stream,
                       feb, fpb, wjb, b_joint, Abuf, out, 0, MTOT);
    hipLaunchKernelGGL(k_joint7s, dim3(grid), dim3(256), 0, stream,
                       Abuf, wjb, b_joint, out, 0, MTOT, nmt);
  } else if (ws_size >= BATCH_NEED){
    const int nmt = 158;                        // ceil(20200/128)
    const int grid = 8 * 8 * ((nmt + 7) / 8);   // 1280
    for (int b = 0; b < 8; b++){
      hipLaunchKernelGGL(k_tanhA, dim3(MB_ / 4), dim3(256), 0, stream,
                         feb, fpb, wjb, b_joint, Abuf, out, b * MB_, MB_);
      hipLaunchKernelGGL(k_joint7s, dim3(grid), dim3(256), 0, stream,
                         Abuf, wjb, b_joint, out, b * MB_, MB_, nmt);
    }
  } else {
    const int nmt = 40;                         // ceil(5050/128)
    const int grid = 8 * 8 * ((nmt + 7) / 8);   // 320
    for (int c = 0; c < 32; c++){
      hipLaunchKernelGGL(k_tanhA, dim3(5050 / 2, 1), dim3(256), 0, stream,
                         feb, fpb, wjb, b_joint, Abuf, out, c * 5050, 5050);
      hipLaunchKernelGGL(k_joint7s, dim3(grid), dim3(256), 0, stream,
                         Abuf, wjb, b_joint, out, c * 5050, 5050, nmt);
    }
  }
}

// Round 21
// 835.863 us; speedup vs baseline: 1.0559x; 1.0316x over previous
//
#include <hip/hip_runtime.h>
#include <stdint.h>
#include <stddef.h>

#define BB 8
#define TENC 200
#define UU 100
#define UP1 101
#define VP1 1025
#define ED 128
#define PD 512
#define LSTM_NWG 64
#define MTOT 161600   // 8*200*101 flattened output rows
#define MB_  20200    // rows per batch (200*101)

typedef __attribute__((ext_vector_type(8))) unsigned short ushort8;
typedef __attribute__((ext_vector_type(8))) __bf16 bf16x8;
typedef __attribute__((ext_vector_type(4))) float f32x4;

__device__ __forceinline__ float bf2f(unsigned short u){
  unsigned int x = ((unsigned int)u) << 16;
  return __builtin_bit_cast(float, x);
}
__device__ __forceinline__ unsigned short f2bf(float f){
  unsigned int x = __builtin_bit_cast(unsigned int, f);
  unsigned int r = (x + 0x7fffu + ((x >> 16) & 1u)) >> 16;
  return (unsigned short)r;
}
__device__ __forceinline__ float tanh_fast(float x){
  float e = __expf(2.0f * x);
  return 1.0f - 2.0f / (e + 1.0f);
}
__device__ __forceinline__ float sigm(float x){
  return 1.0f / (1.0f + __expf(-x));
}
__device__ __forceinline__ void gload_lds16(const unsigned short* gsrc, unsigned short* ldst){
  __builtin_amdgcn_global_load_lds((const __attribute__((address_space(1))) void*)gsrc,
                                   (__attribute__((address_space(3))) void*)ldst, 16, 0, 0);
}

// ---------------- fp32 -> bf16 convert (W_joint) + zero seq flags ----------------
__global__ __launch_bounds__(256) void k_cvt_bf16(const float* __restrict__ src,
                                                  unsigned short* __restrict__ dst, int n,
                                                  unsigned int* __restrict__ seq){
  if (blockIdx.x == 0){
    #pragma unroll
    for (int j = 0; j < 4; j++) seq[threadIdx.x + 256 * j] = 0u;   // 4KB flag area
  }
  int i = blockIdx.x * 256 + threadIdx.x;
  if (i < n) dst[i] = f2bf(src[i]);
}

// ---------------- K1: embedding + x-part of LSTM gates ----------------
__global__ __launch_bounds__(256) void k_xgate(
    const float* __restrict__ emb, const int* __restrict__ targets,
    const float* __restrict__ W_ih, const float* __restrict__ b_ih,
    const float* __restrict__ b_hh, float* __restrict__ xg)
{
  __shared__ float e_s[BB * ED];
  const int u  = blockIdx.x >> 2;
  const int jq = blockIdx.x & 3;
  const int tid = threadIdx.x;
  for (int idx = tid; idx < BB * ED; idx += 256){
    int b = idx >> 7, e = idx & 127;
    int tok = (u == 0) ? 1024 : targets[b * UU + (u - 1)];
    e_s[idx] = emb[(size_t)tok * ED + e];
  }
  __syncthreads();
  float acc[2][BB];
  #pragma unroll
  for (int r = 0; r < 2; r++)
    #pragma unroll
    for (int b = 0; b < BB; b++) acc[r][b] = 0.0f;
  const int j0 = jq * 512 + tid;
  const float* w0p = W_ih + (size_t)j0 * ED;
  const float* w1p = W_ih + (size_t)(j0 + 256) * ED;
  for (int e = 0; e < ED; e++){
    float w0 = w0p[e], w1 = w1p[e];
    #pragma unroll
    for (int b = 0; b < BB; b++){
      float ev = e_s[b * ED + e];
      acc[0][b] = fmaf(ev, w0, acc[0][b]);
      acc[1][b] = fmaf(ev, w1, acc[1][b]);
    }
  }
  #pragma unroll
  for (int r = 0; r < 2; r++){
    int j = j0 + r * 256;
    float bias = b_ih[j] + b_hh[j];
    #pragma unroll
    for (int b = 0; b < BB; b++)
      xg[((size_t)b * UP1 + u) * 2048 + j] = acc[r][b] + bias;
  }
}

// ---------------- K2: fused persistent LSTM (blocks 0..63) + f_enc GEMM (blocks 64..263) ----
// LSTM: R3 register-blocked dot + padded flag-array sync (identical logic to r18 build).
// GEMM blocks compute feb = f2bf(enc_out @ W_enc^T + b_enc), filling the 192 idle CUs.
// Deadlock-free by capacity: worst-case the 200 GEMM blocks occupy <=67 CUs (3/CU via
// 50.7KB LDS), leaving >=189 CUs for the 64 co-resident LSTM blocks.
__global__ __launch_bounds__(256) void k_lstm_enc(
    const float* __restrict__ xg, const float* __restrict__ W_hh,
    float* __restrict__ pred, float* __restrict__ hb, unsigned int* __restrict__ seq,
    const float* __restrict__ encA, const float* __restrict__ W_enc,
    const float* __restrict__ b_enc, unsigned short* __restrict__ feb)
{
  __shared__ char smem[50688];
  const int tid = threadIdx.x;

  if (blockIdx.x >= LSTM_NWG){
    // ---- f_enc GEMM body (M=1600, grid 25 x 8) ----
    float (*a_s)[68] = (float(*)[68])smem;
    float (*b_s)[68] = (float(*)[68])(smem + 4352);
    const int bid2 = blockIdx.x - LSTM_NWG;
    const int m0 = (bid2 % 25) * 64, n0 = (bid2 / 25) * 64;
    const int tx = tid & 15, ty = tid >> 4;
    float acc[4][4];
    #pragma unroll
    for (int i2 = 0; i2 < 4; i2++)
      #pragma unroll
      for (int j2 = 0; j2 < 4; j2++) acc[i2][j2] = 0.0f;
    for (int k0 = 0; k0 < 512; k0 += 16){
      int mm = tid >> 2, k4 = (tid & 3) * 4;
      int row = m0 + mm; if (row >= 1600) row = 1599;
      float4 av = *(const float4*)(encA + (size_t)row * 512 + k0 + k4);
      a_s[k4 + 0][mm] = av.x; a_s[k4 + 1][mm] = av.y;
      a_s[k4 + 2][mm] = av.z; a_s[k4 + 3][mm] = av.w;
      float4 bv = *(const float4*)(W_enc + (size_t)(n0 + mm) * 512 + k0 + k4);
      b_s[k4 + 0][mm] = bv.x; b_s[k4 + 1][mm] = bv.y;
      b_s[k4 + 2][mm] = bv.z; b_s[k4 + 3][mm] = bv.w;
      __syncthreads();
      #pragma unroll
      for (int k = 0; k < 16; k++){
        float4 a4 = *(const float4*)&a_s[k][ty * 4];
        float4 b4 = *(const float4*)&b_s[k][tx * 4];
        float aa[4] = {a4.x, a4.y, a4.z, a4.w};
        float bb[4] = {b4.x, b4.y, b4.z, b4.w};
        #pragma unroll
        for (int i2 = 0; i2 < 4; i2++)
          #pragma unroll
          for (int j2 = 0; j2 < 4; j2++)
            acc[i2][j2] = fmaf(aa[i2], bb[j2], acc[i2][j2]);
      }
      __syncthreads();
    }
    #pragma unroll
    for (int i2 = 0; i2 < 4; i2++){
      int m = m0 + ty * 4 + i2;
      if (m < 1600){
        #pragma unroll
        for (int j2 = 0; j2 < 4; j2++){
          int n = n0 + tx * 4 + j2;
          feb[(size_t)m * 512 + n] = f2bf(acc[i2][j2] + b_enc[n]);
        }
      }
    }
    return;
  }

  // ---- LSTM body (identical to r18 k_lstm_all) ----
  float (*h_s)[520]    = (float(*)[520])smem;                 // 16,640 B
  float *red           = (float*)(smem + 16640);              // 32,896 B
  float (*gates_s)[9]  = (float(*)[9])(smem + 16640 + 32896); //  1,152 B
  const int wg  = blockIdx.x;
  const int p0  = wg * 8;
  const int jg = tid >> 5, kc = tid & 31;
  const float* wrow[4];
  #pragma unroll
  for (int r = 0; r < 4; r++){
    int jl = jg * 4 + r;
    int grow = (jl >> 3) * PD + p0 + (jl & 7);
    wrow[r] = W_hh + (size_t)grow * PD;
  }
  float c_reg = 0.0f;
  for (int u = 0; u < UP1; u++){
    float xi = 0.f, xf = 0.f, xgv = 0.f, xo = 0.f;
    if (tid < 64){
      int pl = tid >> 3, b = tid & 7;
      const float* xr = xg + ((size_t)(b * UP1 + u)) * 2048;
      int p = p0 + pl;
      xi = xr[p]; xf = xr[512 + p]; xgv = xr[1024 + p]; xo = xr[1536 + p];
    }
    if (u > 0){
      if (tid < 64){
        while (1){
          unsigned int v = __hip_atomic_load(&seq[tid * 16], __ATOMIC_RELAXED, __HIP_MEMORY_SCOPE_AGENT);
          if (__all(v >= (unsigned int)u)) break;
          __builtin_amdgcn_s_sleep(1);
        }
      }
      __syncthreads();
      const float* hsrc = hb + ((u - 1) & 1) * 4096;
      float tmp[16];
      #pragma unroll
      for (int j = 0; j < 16; j++)
        tmp[j] = __hip_atomic_load(hsrc + tid + 256 * j,
                                   __ATOMIC_RELAXED, __HIP_MEMORY_SCOPE_AGENT);
      #pragma unroll
      for (int j = 0; j < 16; j++){
        int i = tid + 256 * j;
        h_s[i >> 9][i & 511] = tmp[j];
      }
    } else {
      for (int i = tid; i < 8 * PD; i += 256) h_s[i >> 9][i & 511] = 0.0f;
    }
    __syncthreads();
    float acc[4][BB];
    #pragma unroll
    for (int r = 0; r < 4; r++)
      #pragma unroll
      for (int b = 0; b < BB; b++) acc[r][b] = 0.0f;
    for (int i = 0; i < 16; i++){
      int k = kc + 32 * i;
      float hv[BB];
      #pragma unroll
      for (int b = 0; b < BB; b++) hv[b] = h_s[b][k];
      #pragma unroll
      for (int r = 0; r < 4; r++){
        float wv = wrow[r][k];
        #pragma unroll
        for (int b = 0; b < BB; b++) acc[r][b] = fmaf(hv[b], wv, acc[r][b]);
      }
    }
    #pragma unroll
    for (int r = 0; r < 4; r++)
      #pragma unroll
      for (int b = 0; b < BB; b++)
        red[kc * 257 + jg * 32 + r * 8 + b] = acc[r][b];
    __syncthreads();
    {
      int jl = tid >> 3, b = tid & 7;
      float s = 0.0f;
      #pragma unroll
      for (int kk = 0; kk < 32; kk++)
        s += red[kk * 257 + (jl >> 2) * 32 + (jl & 3) * 8 + b];
      gates_s[jl][b] = s;
    }
    __syncthreads();
    if (tid < 64){
      int pl = tid >> 3, b2 = tid & 7;
      int p = p0 + pl;
      float gi = gates_s[0  + pl][b2] + xi;
      float gf = gates_s[8  + pl][b2] + xf;
      float gg = gates_s[16 + pl][b2] + xgv;
      float go = gates_s[24 + pl][b2] + xo;
      float iv = sigm(gi), fv = sigm(gf), ov = sigm(go);
      c_reg = fv * c_reg + iv * tanh_fast(gg);
      float hval = ov * tanh_fast(c_reg);
      __hip_atomic_store(hb + (u & 1) * 4096 + b2 * 512 + p, hval,
                         __ATOMIC_RELAXED, __HIP_MEMORY_SCOPE_AGENT);
      pred[((size_t)(b2 * UP1 + u)) * PD + p] = hval;
    }
    if (u < UP1 - 1 && tid == 0){
      asm volatile("s_waitcnt vmcnt(0)" ::: "memory");  // wave-0 h stores retired
      __hip_atomic_store(&seq[wg * 16], (unsigned int)(u + 1),
                         __ATOMIC_RELAXED, __HIP_MEMORY_SCOPE_AGENT);
    }
  }
}

// ---------------- K3: fp32 GEMM (A @ W^T + bias) -> bf16 out (fp side) ----------------
__global__ __launch_bounds__(256) void k_gemm_bias_bf16(
    const float* __restrict__ A, const float* __restrict__ W,
    const float* __restrict__ bias, unsigned short* __restrict__ out, int M)
{
  __shared__ float a_s[16][68];
  __shared__ float b_s[16][68];
  const int m0 = blockIdx.x * 64, n0 = blockIdx.y * 64;
  const int tid = threadIdx.x;
  const int tx = tid & 15, ty = tid >> 4;
  float acc[4][4];
  #pragma unroll
  for (int i2 = 0; i2 < 4; i2++)
    #pragma unroll
    for (int j2 = 0; j2 < 4; j2++) acc[i2][j2] = 0.0f;
  for (int k0 = 0; k0 < 512; k0 += 16){
    int mm = tid >> 2, k4 = (tid & 3) * 4;
    int row = m0 + mm; if (row >= M) row = M - 1;
    float4 av = *(const float4*)(A + (size_t)row * 512 + k0 + k4);
    a_s[k4 + 0][mm] = av.x; a_s[k4 + 1][mm] = av.y;
    a_s[k4 + 2][mm] = av.z; a_s[k4 + 3][mm] = av.w;
    float4 bv = *(const float4*)(W + (size_t)(n0 + mm) * 512 + k0 + k4);
    b_s[k4 + 0][mm] = bv.x; b_s[k4 + 1][mm] = bv.y;
    b_s[k4 + 2][mm] = bv.z; b_s[k4 + 3][mm] = bv.w;
    __syncthreads();
    #pragma unroll
    for (int k = 0; k < 16; k++){
      float4 a4 = *(const float4*)&a_s[k][ty * 4];
      float4 b4 = *(const float4*)&b_s[k][tx * 4];
      float aa[4] = {a4.x, a4.y, a4.z, a4.w};
      float bb[4] = {b4.x, b4.y, b4.z, b4.w};
      #pragma unroll
      for (int i2 = 0; i2 < 4; i2++)
        #pragma unroll
        for (int j2 = 0; j2 < 4; j2++)
          acc[i2][j2] = fmaf(aa[i2], bb[j2], acc[i2][j2]);
    }
    __syncthreads();
  }
  #pragma unroll
  for (int i2 = 0; i2 < 4; i2++){
    int m = m0 + ty * 4 + i2;
    if (m < M){
      #pragma unroll
      for (int j2 = 0; j2 < 4; j2++){
        int n = n0 + tx * 4 + j2;
        out[(size_t)m * 512 + n] = f2bf(acc[i2][j2] + bias[n]);
      }
    }
  }
}

// ---------------- K4a: precompute A = tanh(fe+fp) bf16, + fused blank column ----------------
__global__ __launch_bounds__(256) void k_tanhA(
    const unsigned short* __restrict__ fe, const unsigned short* __restrict__ fp,
    const unsigned short* __restrict__ wj, const float* __restrict__ bj,
    unsigned short* __restrict__ Aout, float* __restrict__ out,
    int m_base, int M_cnt)
{
  const int tid = threadIdx.x;
  const int mlocal = blockIdx.x * 4 + (tid >> 6);
  if (mlocal >= M_cnt) return;
  const int l = tid & 63;
  const int m = m_base + mlocal;
  const int q = m / 101;            // b*200 + t
  const int u = m - q * 101;
  const int b = q / 200;
  ushort8 f8 = *(const ushort8*)(fe + (size_t)q * 512 + l * 8);
  ushort8 p8 = *(const ushort8*)(fp + (size_t)(b * 101 + u) * 512 + l * 8);
  ushort8 w8 = *(const ushort8*)(wj + (size_t)1024 * 512 + l * 8);
  ushort8 a;
  float s = 0.0f;
  #pragma unroll
  for (int e = 0; e < 8; e++){
    float v = tanh_fast(bf2f(f8[e]) + bf2f(p8[e]));
    a[e] = f2bf(v);
    s += v * bf2f(w8[e]);
  }
  *(ushort8*)(Aout + (size_t)mlocal * 512 + l * 8) = a;
  #pragma unroll
  for (int off = 1; off < 64; off <<= 1) s += __shfl_xor(s, off);
  if (l == 0) out[(size_t)m * VP1 + 1024] = s + bj[1024];
}

// ---------------- K4b: joint GEMM, XCD-swizzled grid, BK=32, 4 blocks/CU,
//                  counted-vmcnt pipeline (stage(kc+1) stays in flight across barriers) ----
__global__ __launch_bounds__(256, 4) void k_joint7s(
    const unsigned short* __restrict__ A, const unsigned short* __restrict__ wj,
    const float* __restrict__ bj, float* __restrict__ out,
    int m_base, int M_cnt, int nmt)
{
  __shared__ unsigned short A_s[2][128 * 32];   // 2 x 8KB
  __shared__ unsigned short B_s[2][128 * 32];   // 2 x 8KB
  const int bid = blockIdx.x;
  const int mt  = (bid >> 6) * 8 + (bid & 7);   // m-tile
  if (mt >= nmt) return;
  const int m0 = mt * 128;
  const int n0 = ((bid >> 3) & 7) * 128;
  const int tid = threadIdx.x;
  const int w = tid >> 6, l = tid & 63;
  const int l15 = l & 15, lg = l >> 4;
  const int wr = w >> 1, wc = w & 1;

  auto stage = [&](int buf, int kc){
    #pragma unroll
    for (int i = 0; i < 2; i++){
      int sbase = i * 256 + w * 64;            // wave-uniform slot base
      int slot  = sbase + l;
      int r  = slot >> 2;                      // row 0..127
      int cs = slot & 3;                       // 16B sub-chunk 0..3
      int col8 = cs ^ ((r >> 1) & 3);          // pre-swizzled source
      int ra = m0 + r; if (ra >= M_cnt) ra = M_cnt - 1;
      gload_lds16(A + (size_t)ra * 512 + kc * 32 + col8 * 8,
                  (unsigned short*)A_s[buf] + (size_t)sbase * 8);
      gload_lds16(wj + (size_t)(n0 + r) * 512 + kc * 32 + col8 * 8,
                  (unsigned short*)B_s[buf] + (size_t)sbase * 8);
    }
  };

  stage(0, 0);
  __syncthreads();   // drains vmcnt: buf0 resident for all waves

  f32x4 acc[4][4];
  #pragma unroll
  for (int fr = 0; fr < 4; fr++)
    #pragma unroll
    for (int fc = 0; fc < 4; fc++)
      acc[fr][fc] = (f32x4){0.f, 0.f, 0.f, 0.f};

  for (int kc = 0; kc < 16; kc++){
    const int buf = kc & 1;
    if (kc < 15){
      stage(buf ^ 1, kc + 1);                            // 4 loads, stay in flight
      asm volatile("s_waitcnt vmcnt(4)" ::: "memory");   // stage(kc) (issued last iter) landed
    } else {
      asm volatile("s_waitcnt vmcnt(0)" ::: "memory");
    }
    __builtin_amdgcn_s_barrier();                        // all waves' stage(kc) chunks resident

    bf16x8 afr[4], bfr[4];
    #pragma unroll
    for (int f = 0; f < 4; f++){
      int ra = wr * 64 + f * 16 + l15;
      int bya = ra * 64 + ((lg ^ ((ra >> 1) & 3)) * 16);
      afr[f] = __builtin_bit_cast(bf16x8, *(const ushort8*)((const char*)A_s[buf] + bya));
      int rb = wc * 64 + f * 16 + l15;
      int byb = rb * 64 + ((lg ^ ((rb >> 1) & 3)) * 16);
      bfr[f] = __builtin_bit_cast(bf16x8, *(const ushort8*)((const char*)B_s[buf] + byb));
    }
    #pragma unroll
    for (int fr = 0; fr < 4; fr++)
      #pragma unroll
      for (int fc = 0; fc < 4; fc++)
        acc[fr][fc] = __builtin_amdgcn_mfma_f32_16x16x32_bf16(bfr[fc], afr[fr], acc[fr][fc], 0, 0, 0);
    __builtin_amdgcn_s_barrier();                        // all waves done reading buf
  }

  // epilogue: C reg-dim = n (col), lane l15 = m (row)
  #pragma unroll
  for (int fr = 0; fr < 4; fr++){
    int mloc = m0 + wr * 64 + fr * 16 + l15;
    if (mloc < M_cnt){
      float* orow = out + (size_t)(m_base + mloc) * VP1;
      #pragma unroll
      for (int fc = 0; fc < 4; fc++){
        int col = n0 + wc * 64 + fc * 16 + lg * 4;
        float4 bv = *(const float4*)(bj + col);
        f32x4 v = acc[fr][fc];
        float4 st = {v[0] + bv.x, v[1] + bv.y, v[2] + bv.z, v[3] + bv.w};
        *(float4*)(orow + col) = st;
      }
    }
  }
}

extern "C" void kernel_launch(void* const* d_in, const int* in_sizes, int n_in,
                              void* d_out, int out_size, void* d_ws, size_t ws_size,
                              hipStream_t stream) {
  const float* enc_out = (const float*)d_in[0];
  const int*   targets = (const int*)d_in[1];
  const float* emb     = (const float*)d_in[3];
  const float* W_ih    = (const float*)d_in[4];
  const float* W_hh    = (const float*)d_in[5];
  const float* b_ih    = (const float*)d_in[6];
  const float* b_hh    = (const float*)d_in[7];
  const float* W_enc   = (const float*)d_in[8];
  const float* b_enc   = (const float*)d_in[9];
  const float* W_pred  = (const float*)d_in[10];
  const float* b_pred  = (const float*)d_in[11];
  const float* W_joint = (const float*)d_in[12];
  const float* b_joint = (const float*)d_in[13];
  float* out = (float*)d_out;

  char* ws = (char*)d_ws;
  float* xg            = (float*)(ws + 0);                  // 6,619,136 B
  float* pred          = (float*)(ws + 6619136);            // 1,654,784 B
  unsigned short* feb  = (unsigned short*)(ws + 8273920);   // 1,638,400 B
  unsigned short* fpb  = (unsigned short*)(ws + 9912320);   //   827,392 B
  unsigned short* wjb  = (unsigned short*)(ws + 10739712);  // 1,049,600 B
  float* hb            = (float*)(ws + 11789312);           //    32,768 B
  unsigned int* seq    = (unsigned int*)(ws + 11822080);    //     4,096 B (64 x 64B lines)
  unsigned short* Abuf = (unsigned short*)(ws + 11827200);  // A workspace
  const size_t FULL_NEED  = 11827200 + (size_t)MTOT * 512 * 2;  // ~177.3 MB
  const size_t BATCH_NEED = 11827200 + (size_t)MB_  * 512 * 2;  // ~32.5 MB

  hipLaunchKernelGGL(k_cvt_bf16, dim3((VP1 * 512 + 255) / 256), dim3(256), 0, stream,
                     W_joint, wjb, VP1 * 512, seq);
  hipLaunchKernelGGL(k_xgate, dim3(404), dim3(256), 0, stream,
                     emb, targets, W_ih, b_ih, b_hh, xg);
  hipLaunchKernelGGL(k_lstm_enc, dim3(LSTM_NWG + 200), dim3(256), 0, stream,
                     xg, W_hh, pred, hb, seq, enc_out, W_enc, b_enc, feb);
  hipLaunchKernelGGL(k_gemm_bias_bf16, dim3(13, 8), dim3(256), 0, stream,
                     pred, W_pred, b_pred, fpb, 808);

  if (ws_size >= FULL_NEED){
    const int nmt = 1263;                       // ceil(161600/128)
    const int grid = 8 * 8 * ((nmt + 7) / 8);   // 10112
    hipLaunchKernelGGL(k_tanhA, dim3(MTOT / 4), dim3(256), 0, stream,
                       feb, fpb, wjb, b_joint, Abuf, out, 0, MTOT);
    hipLaunchKernelGGL(k_joint7s, dim3(grid), dim3(256), 0, stream,
                       Abuf, wjb, b_joint, out, 0, MTOT, nmt);
  } else if (ws_size >= BATCH_NEED){
    const int nmt = 158;                        // ceil(20200/128)
    const int grid = 8 * 8 * ((nmt + 7) / 8);   // 1280
    for (int b = 0; b < 8; b++){
      hipLaunchKernelGGL(k_tanhA, dim3(MB_ / 4), dim3(256), 0, stream,
                         feb, fpb, wjb, b_joint, Abuf, out, b * MB_, MB_);
      hipLaunchKernelGGL(k_joint7s, dim3(grid), dim3(256), 0, stream,
                         Abuf, wjb, b_joint, out, b * MB_, MB_, nmt);
    }
  } else {
    const int nmt = 40;                         // ceil(5050/128)
    const int grid = 8 * 8 * ((nmt + 7) / 8);   // 320
    for (int c = 0; c < 32; c++){
      hipLaunchKernelGGL(k_tanhA, dim3(5050 / 2, 1), dim3(256), 0, stream,
                         feb, fpb, wjb, b_joint, Abuf, out, c * 5050, 5050);
      hipLaunchKernelGGL(k_joint7s, dim3(grid), dim3(256), 0, stream,
                         Abuf, wjb, b_joint, out, c * 5050, 5050, nmt);
    }
  }
}